// Round 4
// baseline (41.830 us; speedup 1.0000x reference)
//
#include <hip/hip_runtime.h>
#include <math.h>

#define DD_ 256
#define HH_ 512
#define OO_ 64

typedef __attribute__((ext_vector_type(8))) short bf16x8s;
typedef __attribute__((ext_vector_type(4))) float f32x4;

__device__ __forceinline__ unsigned short f2bf(float f) {
    unsigned u = __float_as_uint(f);
    u += 0x7FFF + ((u >> 16) & 1);   // round-to-nearest-even
    return (unsigned short)(u >> 16);
}
__device__ __forceinline__ float bf2f(unsigned short h) {
    return __uint_as_float(((unsigned)h) << 16);
}
// XOR swizzle of the 16B slot within a 64B LDS row: 2-way-max bank aliasing
__device__ __forceinline__ int swz4(int r, int g) {
    return g ^ (r & 3) ^ ((r >> 2) & 3);
}

// ============ K0: prep — all fp32->bf16 hi/lo conversions hoisted ============
// bb<64: gather x rows -> xhi/xlo [4096][256]
// bb in [64,192): Xt[256][6144] bf16 (4 jblk x 32 pblk)
// bb in [192,208): W1 -> w1hi/w1lo [512][256]
// bb in [208,210): c[i] = sum_o W2[o][i]^2
__global__ __launch_bounds__(256) void k_prep(
    const float* __restrict__ x, const float* __restrict__ W1, const float* __restrict__ W2,
    const int* __restrict__ ap, const int* __restrict__ pI,
    const int* __restrict__ an, const int* __restrict__ nI,
    short* __restrict__ xhi, short* __restrict__ xlo,
    short* __restrict__ w1hi, short* __restrict__ w1lo,
    float* __restrict__ c, short* __restrict__ Xt) {
    const int t = threadIdx.x;
    const int bb = blockIdx.x;
    if (bb < 64) {
        const int r = bb * 64 + (t >> 2), q = t & 3;   // 4 threads/row, 64 els each
        const int set = r >> 10;
        const int* I = (set == 0) ? ap : (set == 1) ? pI : (set == 2) ? an : nI;
        const int idx = I[r & 1023];
        const float* src = x + (size_t)idx * DD_ + q * 64;
        const size_t dst = (size_t)r * DD_ + q * 64;
        #pragma unroll
        for (int jj = 0; jj < 8; ++jj) {
            float4 v0 = *(const float4*)(src + jj * 8);
            float4 v1 = *(const float4*)(src + jj * 8 + 4);
            float f[8] = {v0.x, v0.y, v0.z, v0.w, v1.x, v1.y, v1.z, v1.w};
            bf16x8s hi, lo;
            #pragma unroll
            for (int e = 0; e < 8; ++e) {
                unsigned short hh = f2bf(f[e]);
                hi[e] = (short)hh;
                lo[e] = (short)f2bf(f[e] - bf2f(hh));
            }
            *(bf16x8s*)(&xhi[dst + jj * 8]) = hi;
            *(bf16x8s*)(&xlo[dst + jj * 8]) = lo;
        }
    } else if (bb < 192) {
        __shared__ int sia[64], sib[64];
        const int b2 = bb - 64;
        const int jblk = b2 >> 5, pblk = b2 & 31;
        const int j = jblk * 64 + (t >> 2), pq = t & 3;
        const int p0 = pblk * 64;
        const int s = p0 >> 10;
        const int* IA = s ? an : ap;
        const int* IB = s ? nI : pI;
        if (t < 64) sia[t] = IA[(p0 & 1023) + t];
        else if (t < 128) sib[t - 64] = IB[(p0 & 1023) + (t - 64)];
        __syncthreads();
        short xv[3][16];
        #pragma unroll
        for (int pp = 0; pp < 16; ++pp) {
            int pl = pq * 16 + pp;
            float xa = x[(size_t)sia[pl] * DD_ + j];
            float xb = x[(size_t)sib[pl] * DD_ + j];
            xv[0][pp] = (short)f2bf(xa * xa);
            xv[1][pp] = (short)f2bf(xa * xb);
            xv[2][pp] = (short)f2bf(xb * xb);
        }
        size_t base = (size_t)j * 6144 + p0 + pq * 16;
        #pragma unroll
        for (int term = 0; term < 3; ++term) {
            bf16x8s v0, v1;
            #pragma unroll
            for (int e = 0; e < 8; ++e) { v0[e] = xv[term][e]; v1[e] = xv[term][e + 8]; }
            *(bf16x8s*)(&Xt[base + (size_t)term * 2048]) = v0;
            *(bf16x8s*)(&Xt[base + (size_t)term * 2048 + 8]) = v1;
        }
    } else if (bb < 208) {
        const int b3 = bb - 192;
        const int r = b3 * 32 + (t >> 3), q = t & 7;   // 8 threads/row, 32 els each
        const float* src = W1 + (size_t)r * DD_ + q * 32;
        const size_t dst = (size_t)r * DD_ + q * 32;
        #pragma unroll
        for (int jj = 0; jj < 4; ++jj) {
            float4 v0 = *(const float4*)(src + jj * 8);
            float4 v1 = *(const float4*)(src + jj * 8 + 4);
            float f[8] = {v0.x, v0.y, v0.z, v0.w, v1.x, v1.y, v1.z, v1.w};
            bf16x8s hi, lo;
            #pragma unroll
            for (int e = 0; e < 8; ++e) {
                unsigned short hh = f2bf(f[e]);
                hi[e] = (short)hh;
                lo[e] = (short)f2bf(f[e] - bf2f(hh));
            }
            *(bf16x8s*)(&w1hi[dst + jj * 8]) = hi;
            *(bf16x8s*)(&w1lo[dst + jj * 8]) = lo;
        }
    } else {
        const int i = (bb - 208) * 256 + t;
        float s = 0.f;
        #pragma unroll
        for (int o = 0; o < OO_; ++o) { float w = W2[o * HH_ + i]; s += w * w; }
        c[i] = s;
    }
}

// ============ K1: h = tanh(xg . W1g^T + b1), split-bf16 MFMA, pure-copy staging ====
// grid (8 nblk, 64 mblk); block 64m x 64n, 4 waves of 32x32; K=256
__global__ __launch_bounds__(256) void k_gemm1(
    const short* __restrict__ xhi, const short* __restrict__ xlo,
    const short* __restrict__ w1hi, const short* __restrict__ w1lo,
    const float* __restrict__ b1, float* __restrict__ h) {
    __shared__ short Ah[64 * 32], Al[64 * 32], Bh[64 * 32], Bl[64 * 32];
    const int t = threadIdx.x;
    const int n0 = blockIdx.x * 64;
    const int rbase = blockIdx.y * 64;
    const int row = t >> 2, q = t & 3;          // staging: row 0..63, 16B slot 0..3
    const int l = t & 63, w = t >> 6;
    const int wm = w >> 1, wn = w & 1;          // wave 2x2 over 64x64 tile
    const int lm = l & 15, g = l >> 4;          // frag: m/n = lm, k-slot = g
    const int sw = swz4(row, q);
    f32x4 acc[2][2] = {};
    for (int k0 = 0; k0 < DD_; k0 += 32) {
        const size_t asrc = (size_t)(rbase + row) * DD_ + k0 + q * 8;
        const size_t bsrc = (size_t)(n0 + row) * DD_ + k0 + q * 8;
        *(bf16x8s*)(&Ah[(row * 4 + sw) * 8]) = *(const bf16x8s*)(&xhi[asrc]);
        *(bf16x8s*)(&Al[(row * 4 + sw) * 8]) = *(const bf16x8s*)(&xlo[asrc]);
        *(bf16x8s*)(&Bh[(row * 4 + sw) * 8]) = *(const bf16x8s*)(&w1hi[bsrc]);
        *(bf16x8s*)(&Bl[(row * 4 + sw) * 8]) = *(const bf16x8s*)(&w1lo[bsrc]);
        __syncthreads();
        bf16x8s ah[2], al[2], bh[2], bl[2];
        #pragma unroll
        for (int mi = 0; mi < 2; ++mi) {
            int r = wm * 32 + mi * 16 + lm;
            ah[mi] = *(const bf16x8s*)(&Ah[(r * 4 + swz4(r, g)) * 8]);
            al[mi] = *(const bf16x8s*)(&Al[(r * 4 + swz4(r, g)) * 8]);
        }
        #pragma unroll
        for (int nj = 0; nj < 2; ++nj) {
            int r = wn * 32 + nj * 16 + lm;
            bh[nj] = *(const bf16x8s*)(&Bh[(r * 4 + swz4(r, g)) * 8]);
            bl[nj] = *(const bf16x8s*)(&Bl[(r * 4 + swz4(r, g)) * 8]);
        }
        #pragma unroll
        for (int mi = 0; mi < 2; ++mi)
            #pragma unroll
            for (int nj = 0; nj < 2; ++nj) {
                acc[mi][nj] = __builtin_amdgcn_mfma_f32_16x16x32_bf16(ah[mi], bh[nj], acc[mi][nj], 0, 0, 0);
                acc[mi][nj] = __builtin_amdgcn_mfma_f32_16x16x32_bf16(ah[mi], bl[nj], acc[mi][nj], 0, 0, 0);
                acc[mi][nj] = __builtin_amdgcn_mfma_f32_16x16x32_bf16(al[mi], bh[nj], acc[mi][nj], 0, 0, 0);
            }
        __syncthreads();
    }
    #pragma unroll
    for (int mi = 0; mi < 2; ++mi)
        #pragma unroll
        for (int nj = 0; nj < 2; ++nj) {
            int j = n0 + wn * 32 + nj * 16 + lm;
            float bv = b1[j];
            #pragma unroll
            for (int qq = 0; qq < 4; ++qq) {
                int r = rbase + wm * 32 + mi * 16 + g * 4 + qq;   // D row = (l>>4)*4+reg
                h[(size_t)r * HH_ + j] = tanhf(acc[mi][nj][qq] + bv);
            }
        }
}

// ============ K2: build Mt[512][6144] bf16 + b1/hd partials ====
// grid 256 = 8 iblk x 32 pblk
__global__ __launch_bounds__(256) void k_buildM(
    const float* __restrict__ h, const float* __restrict__ c,
    short* __restrict__ Mt, float* __restrict__ pb1, float* __restrict__ phd) {
    const int t = threadIdx.x;
    const int bb = blockIdx.x;
    const int iblk = bb >> 5, pblk = bb & 31;
    const int i = iblk * 64 + (t >> 2), pq = t & 3;
    const int p0 = pblk * 64;
    const int s = p0 >> 10;
    const float sgn = s ? -1.f : 1.f;
    const float ci = c[i];
    const int pb = (p0 & 1023) + pq * 16;
    const float* hA = h + (size_t)(s * 2048 + pb) * HH_ + i;
    const float* hB = hA + (size_t)1024 * HH_;
    short m[3][16];
    float b1p = 0.f, hdp = 0.f;
    #pragma unroll
    for (int pp = 0; pp < 16; ++pp) {
        float ha = hA[(size_t)pp * HH_];
        float hb = hB[(size_t)pp * HH_];
        float da = 1.f - ha * ha, db = 1.f - hb * hb;
        float s11 = sgn * (da * da * ci);
        float s12 = sgn * (-2.f * da * db * ci);
        float s22 = sgn * (db * db * ci);
        m[0][pp] = (short)f2bf(s11);
        m[1][pp] = (short)f2bf(s12);
        m[2][pp] = (short)f2bf(s22);
        b1p += s11 + s12 + s22;
        float d = ha - hb;
        hdp += sgn * d * d;
    }
    size_t base = (size_t)i * 6144 + p0 + pq * 16;
    #pragma unroll
    for (int term = 0; term < 3; ++term) {
        bf16x8s v0, v1;
        #pragma unroll
        for (int e = 0; e < 8; ++e) { v0[e] = m[term][e]; v1[e] = m[term][e + 8]; }
        *(bf16x8s*)(&Mt[base + (size_t)term * 2048]) = v0;
        *(bf16x8s*)(&Mt[base + (size_t)term * 2048 + 8]) = v1;
    }
    b1p += __shfl_xor(b1p, 1); b1p += __shfl_xor(b1p, 2);
    hdp += __shfl_xor(hdp, 1); hdp += __shfl_xor(hdp, 2);
    if (pq == 0) { pb1[pblk * HH_ + i] = b1p; phd[pblk * HH_ + i] = hdp; }
}

// ============ K3: part[kb][i][j] = sum_{k chunk 384} Mt[i][k]*Xt[j][k], bf16 MFMA ====
// grid (4 jblk, 8 iblk, 16 kb); block 64i x 64j, 4 waves of 32x32
__global__ __launch_bounds__(256) void k_gemm2(
    const short* __restrict__ Mt, const short* __restrict__ Xt,
    float* __restrict__ part) {
    __shared__ short As[64 * 32], Bs[64 * 32];
    const int t = threadIdx.x;
    const int j0 = blockIdx.x * 64;
    const int i0 = blockIdx.y * 64;
    const int kb = blockIdx.z;
    const int row = t >> 2, q = t & 3;
    const int l = t & 63, w = t >> 6;
    const int wm = w >> 1, wn = w & 1;
    const int lm = l & 15, g = l >> 4;
    const int sw = swz4(row, q);
    f32x4 acc[2][2] = {};
    for (int ks = 0; ks < 12; ++ks) {
        const int k0 = kb * 384 + ks * 32;
        *(bf16x8s*)(&As[(row * 4 + sw) * 8]) =
            *(const bf16x8s*)(&Mt[(size_t)(i0 + row) * 6144 + k0 + q * 8]);
        *(bf16x8s*)(&Bs[(row * 4 + sw) * 8]) =
            *(const bf16x8s*)(&Xt[(size_t)(j0 + row) * 6144 + k0 + q * 8]);
        __syncthreads();
        bf16x8s a[2], b[2];
        #pragma unroll
        for (int mi = 0; mi < 2; ++mi) {
            int r = wm * 32 + mi * 16 + lm;
            a[mi] = *(const bf16x8s*)(&As[(r * 4 + swz4(r, g)) * 8]);
        }
        #pragma unroll
        for (int nj = 0; nj < 2; ++nj) {
            int r = wn * 32 + nj * 16 + lm;
            b[nj] = *(const bf16x8s*)(&Bs[(r * 4 + swz4(r, g)) * 8]);
        }
        #pragma unroll
        for (int mi = 0; mi < 2; ++mi)
            #pragma unroll
            for (int nj = 0; nj < 2; ++nj)
                acc[mi][nj] = __builtin_amdgcn_mfma_f32_16x16x32_bf16(a[mi], b[nj], acc[mi][nj], 0, 0, 0);
        __syncthreads();
    }
    #pragma unroll
    for (int mi = 0; mi < 2; ++mi)
        #pragma unroll
        for (int nj = 0; nj < 2; ++nj) {
            int j = j0 + wn * 32 + nj * 16 + lm;
            #pragma unroll
            for (int qq = 0; qq < 4; ++qq) {
                int i = i0 + wm * 32 + mi * 16 + g * 4 + qq;
                part[((size_t)kb * HH_ + i) * DD_ + j] = acc[mi][nj][qq];
            }
        }
}

// ============ K4: reductions + broadcast + zeros ============
__global__ void k_tail(const float* __restrict__ part, const float* __restrict__ pb1,
                       const float* __restrict__ phd, float* __restrict__ out) {
    int gid = blockIdx.x * 256 + threadIdx.x;
    const int HD = HH_ * DD_;   // 131072
    if (gid < HD) {
        float sv = 0.f;
        #pragma unroll
        for (int kb = 0; kb < 16; ++kb) sv += part[(size_t)kb * HD + gid];
        out[gid] = sv;
    } else if (gid < HD + HH_) {
        int i = gid - HD;
        float sv = 0.f;
        #pragma unroll
        for (int kb = 0; kb < 32; ++kb) sv += pb1[kb * HH_ + i];
        out[gid] = sv;
    } else if (gid < HD + HH_ + OO_ * HH_) {
        int i = (gid - HD - HH_) & (HH_ - 1);
        float sv = 0.f;
        #pragma unroll
        for (int kb = 0; kb < 32; ++kb) sv += phd[kb * HH_ + i];
        out[gid] = sv;
    } else if (gid < HD + HH_ + OO_ * HH_ + OO_) {
        out[gid] = 0.f;
    }
}

extern "C" void kernel_launch(void* const* d_in, const int* in_sizes, int n_in,
                              void* d_out, int out_size, void* d_ws, size_t ws_size,
                              hipStream_t stream) {
    const float* x  = (const float*)d_in[0];
    const float* W1 = (const float*)d_in[1];
    const float* b1 = (const float*)d_in[2];
    const float* W2 = (const float*)d_in[3];
    // d_in[4] = b2 (unused: b2 Jacobians cancel)
    const int* ap = (const int*)d_in[5];
    const int* pI = (const int*)d_in[6];
    const int* an = (const int*)d_in[7];
    const int* nI = (const int*)d_in[8];
    float* out = (float*)d_out;
    float* ws = (float*)d_ws;

    // workspace (float units): total ~7.77M floats = 31.1 MB
    float* h    = ws;                         // 4096*512  = 2097152
    float* part = ws + 2097152;               // 16*131072 = 2097152
    short* Mt   = (short*)(ws + 4194304);     // 512*6144 shorts = 1572864 floats
    short* Xt   = (short*)(ws + 5767168);     // 256*6144 shorts =  786432 floats
    float* pb1  = ws + 6553600;               // 32*512
    float* phd  = ws + 6569984;               // 32*512
    short* xhi  = (short*)(ws + 6586368);     // 4096*256 shorts = 524288 floats
    short* xlo  = (short*)(ws + 7110656);
    short* w1hi = (short*)(ws + 7634944);     // 512*256 shorts = 65536 floats
    short* w1lo = (short*)(ws + 7700480);
    float* c    = ws + 7766016;               // 512

    k_prep<<<dim3(210), dim3(256), 0, stream>>>(x, W1, W2, ap, pI, an, nI,
                                                xhi, xlo, w1hi, w1lo, c, Xt);
    k_gemm1<<<dim3(8, 64), dim3(256), 0, stream>>>(xhi, xlo, w1hi, w1lo, b1, h);
    k_buildM<<<dim3(256), dim3(256), 0, stream>>>(h, c, Mt, pb1, phd);
    k_gemm2<<<dim3(4, 8, 16), dim3(256), 0, stream>>>(Mt, Xt, part);
    k_tail<<<dim3(643), dim3(256), 0, stream>>>(part, pb1, phd, out);
}

// Round 5
// 36.014 us; speedup vs baseline: 1.1615x; 1.1615x over previous
//
#include <hip/hip_runtime.h>
#include <math.h>

#define DD_ 256
#define HH_ 512
#define OO_ 64

typedef __attribute__((ext_vector_type(8))) short bf16x8s;
typedef __attribute__((ext_vector_type(4))) float f32x4;

__device__ __forceinline__ unsigned short f2bf(float f) {
    unsigned u = __float_as_uint(f);
    u += 0x7FFF + ((u >> 16) & 1);   // round-to-nearest-even
    return (unsigned short)(u >> 16);
}
__device__ __forceinline__ float bf2f(unsigned short h) {
    return __uint_as_float(((unsigned)h) << 16);
}
// XOR swizzle of the 16B slot within a 64B LDS row: 2-way-max bank aliasing
__device__ __forceinline__ int swz4(int r, int g) {
    return g ^ (r & 3) ^ ((r >> 2) & 3);
}

// ============ K0: Xt[256][6144] bf16, W1 -> hi/lo bf16, c = colsum(W2^2) ============
// bb<128: Xt (4 jblk x 32 pblk); bb in [128,144): W1 conv; bb in [144,146): c
__global__ __launch_bounds__(256) void k_prep(
    const float* __restrict__ x, const float* __restrict__ W1, const float* __restrict__ W2,
    const int* __restrict__ ap, const int* __restrict__ pI,
    const int* __restrict__ an, const int* __restrict__ nI,
    short* __restrict__ w1hi, short* __restrict__ w1lo,
    float* __restrict__ c, short* __restrict__ Xt) {
    const int t = threadIdx.x;
    const int bb = blockIdx.x;
    if (bb < 128) {
        __shared__ int sia[64], sib[64];
        const int jblk = bb >> 5, pblk = bb & 31;
        const int j = jblk * 64 + (t >> 2), pq = t & 3;
        const int p0 = pblk * 64;
        const int s = p0 >> 10;
        const int* IA = s ? an : ap;
        const int* IB = s ? nI : pI;
        if (t < 64) sia[t] = IA[(p0 & 1023) + t];
        else if (t < 128) sib[t - 64] = IB[(p0 & 1023) + (t - 64)];
        __syncthreads();
        short xv[3][16];
        #pragma unroll
        for (int pp = 0; pp < 16; ++pp) {
            int pl = pq * 16 + pp;
            float xa = x[(size_t)sia[pl] * DD_ + j];
            float xb = x[(size_t)sib[pl] * DD_ + j];
            xv[0][pp] = (short)f2bf(xa * xa);
            xv[1][pp] = (short)f2bf(xa * xb);
            xv[2][pp] = (short)f2bf(xb * xb);
        }
        size_t base = (size_t)j * 6144 + p0 + pq * 16;
        #pragma unroll
        for (int term = 0; term < 3; ++term) {
            bf16x8s v0, v1;
            #pragma unroll
            for (int e = 0; e < 8; ++e) { v0[e] = xv[term][e]; v1[e] = xv[term][e + 8]; }
            *(bf16x8s*)(&Xt[base + (size_t)term * 2048]) = v0;
            *(bf16x8s*)(&Xt[base + (size_t)term * 2048 + 8]) = v1;
        }
    } else if (bb < 144) {
        const int b3 = bb - 128;
        const int r = b3 * 32 + (t >> 3), q = t & 7;   // 8 threads/row, 32 els each
        const float* src = W1 + (size_t)r * DD_ + q * 32;
        const size_t dst = (size_t)r * DD_ + q * 32;
        #pragma unroll
        for (int jj = 0; jj < 4; ++jj) {
            float4 v0 = *(const float4*)(src + jj * 8);
            float4 v1 = *(const float4*)(src + jj * 8 + 4);
            float f[8] = {v0.x, v0.y, v0.z, v0.w, v1.x, v1.y, v1.z, v1.w};
            bf16x8s hi, lo;
            #pragma unroll
            for (int e = 0; e < 8; ++e) {
                unsigned short hh = f2bf(f[e]);
                hi[e] = (short)hh;
                lo[e] = (short)f2bf(f[e] - bf2f(hh));
            }
            *(bf16x8s*)(&w1hi[dst + jj * 8]) = hi;
            *(bf16x8s*)(&w1lo[dst + jj * 8]) = lo;
        }
    } else {
        const int i = (bb - 144) * 256 + t;
        float s = 0.f;
        #pragma unroll
        for (int o = 0; o < OO_; ++o) { float w = W2[o * HH_ + i]; s += w * w; }
        c[i] = s;
    }
}

// ============ K1: fused gemm1 + tanh + build Mt + b1/hd partials ============
// grid (8 nblk, 64 ry); ry = s*32 + pb; block owns pairs p0..p0+32 of set s,
// gemm rows 0..31 = a-side, 32..63 = b-side. h never touches global memory.
__global__ __launch_bounds__(256) void k_fused1(
    const float* __restrict__ x,
    const short* __restrict__ w1hi, const short* __restrict__ w1lo,
    const float* __restrict__ b1, const float* __restrict__ c,
    const int* __restrict__ ap, const int* __restrict__ pI,
    const int* __restrict__ an, const int* __restrict__ nI,
    short* __restrict__ Mt, float* __restrict__ pb1, float* __restrict__ phd) {
    __shared__ short Ah[64 * 32], Al[64 * 32], Bh[64 * 32], Bl[64 * 32];
    __shared__ float ht[64][67];   // pad 67: pair-read stride 8*67 mod 32 != 0
    __shared__ int sidx[64];
    const int t = threadIdx.x;
    const int n0 = blockIdx.x * 64;
    const int ry = blockIdx.y;
    const int s = ry >> 5;
    const int p0 = (ry & 31) * 32;
    const int* IA = s ? an : ap;
    const int* IB = s ? nI : pI;
    if (t < 32) sidx[t] = IA[p0 + t];
    else if (t < 64) sidx[t] = IB[p0 + t - 32];
    __syncthreads();
    const int row = t >> 2, q = t & 3;          // staging: row 0..63, 16B slot 0..3
    const int l = t & 63, w = t >> 6;
    const int wm = w >> 1, wn = w & 1;          // wave 2x2 over 64x64 tile
    const int lm = l & 15, g = l >> 4;          // frag: m/n = lm, k-slot = g
    const int sw = swz4(row, q);
    f32x4 acc[2][2] = {};
    for (int k0 = 0; k0 < DD_; k0 += 32) {
        {   // stage A: gathered x rows, fp32 -> bf16 hi/lo on the fly
            const float* src = x + (size_t)sidx[row] * DD_ + k0 + q * 8;
            float4 v0 = *(const float4*)src;
            float4 v1 = *(const float4*)(src + 4);
            float f[8] = {v0.x, v0.y, v0.z, v0.w, v1.x, v1.y, v1.z, v1.w};
            bf16x8s hi, lo;
            #pragma unroll
            for (int e = 0; e < 8; ++e) {
                unsigned short hh = f2bf(f[e]);
                hi[e] = (short)hh;
                lo[e] = (short)f2bf(f[e] - bf2f(hh));
            }
            *(bf16x8s*)(&Ah[(row * 4 + sw) * 8]) = hi;
            *(bf16x8s*)(&Al[(row * 4 + sw) * 8]) = lo;
        }
        {   // stage B: pre-converted W1 hi/lo, pure 16B copies
            const size_t bsrc = (size_t)(n0 + row) * DD_ + k0 + q * 8;
            *(bf16x8s*)(&Bh[(row * 4 + sw) * 8]) = *(const bf16x8s*)(&w1hi[bsrc]);
            *(bf16x8s*)(&Bl[(row * 4 + sw) * 8]) = *(const bf16x8s*)(&w1lo[bsrc]);
        }
        __syncthreads();
        bf16x8s ah[2], al[2], bh[2], bl[2];
        #pragma unroll
        for (int mi = 0; mi < 2; ++mi) {
            int r = wm * 32 + mi * 16 + lm;
            ah[mi] = *(const bf16x8s*)(&Ah[(r * 4 + swz4(r, g)) * 8]);
            al[mi] = *(const bf16x8s*)(&Al[(r * 4 + swz4(r, g)) * 8]);
        }
        #pragma unroll
        for (int nj = 0; nj < 2; ++nj) {
            int r = wn * 32 + nj * 16 + lm;
            bh[nj] = *(const bf16x8s*)(&Bh[(r * 4 + swz4(r, g)) * 8]);
            bl[nj] = *(const bf16x8s*)(&Bl[(r * 4 + swz4(r, g)) * 8]);
        }
        #pragma unroll
        for (int mi = 0; mi < 2; ++mi)
            #pragma unroll
            for (int nj = 0; nj < 2; ++nj) {
                acc[mi][nj] = __builtin_amdgcn_mfma_f32_16x16x32_bf16(ah[mi], bh[nj], acc[mi][nj], 0, 0, 0);
                acc[mi][nj] = __builtin_amdgcn_mfma_f32_16x16x32_bf16(ah[mi], bl[nj], acc[mi][nj], 0, 0, 0);
                acc[mi][nj] = __builtin_amdgcn_mfma_f32_16x16x32_bf16(al[mi], bh[nj], acc[mi][nj], 0, 0, 0);
            }
        __syncthreads();
    }
    // h-tile -> LDS (tanh applied); r<32 = a-side, r>=32 = b-side
    #pragma unroll
    for (int mi = 0; mi < 2; ++mi)
        #pragma unroll
        for (int nj = 0; nj < 2; ++nj) {
            int jl = wn * 32 + nj * 16 + lm;
            float bv = b1[n0 + jl];
            #pragma unroll
            for (int qq = 0; qq < 4; ++qq) {
                int r = wm * 32 + mi * 16 + g * 4 + qq;
                ht[r][jl] = tanhf(acc[mi][nj][qq] + bv);
            }
        }
    __syncthreads();
    // build M + partials: thread (il = t>>2, pq = t&3) handles 8 pairs of column il
    const int il = t >> 2, pq = t & 3;
    const float ci = c[n0 + il];
    const float sgn = s ? -1.f : 1.f;
    float b1p = 0.f, hdp = 0.f;
    bf16x8s v0, v1, v2;
    #pragma unroll
    for (int pp = 0; pp < 8; ++pp) {
        int pl = pq * 8 + pp;
        float ha = ht[pl][il];
        float hb = ht[pl + 32][il];
        float da = 1.f - ha * ha, db = 1.f - hb * hb;
        float s11 = sgn * (da * da * ci);
        float s12 = sgn * (-2.f * da * db * ci);
        float s22 = sgn * (db * db * ci);
        v0[pp] = (short)f2bf(s11);
        v1[pp] = (short)f2bf(s12);
        v2[pp] = (short)f2bf(s22);
        b1p += s11 + s12 + s22;
        float d = ha - hb;
        hdp += sgn * d * d;
    }
    size_t base = (size_t)(n0 + il) * 6144 + s * 1024 + p0 + pq * 8;
    *(bf16x8s*)(&Mt[base]) = v0;
    *(bf16x8s*)(&Mt[base + 2048]) = v1;
    *(bf16x8s*)(&Mt[base + 4096]) = v2;
    b1p += __shfl_xor(b1p, 1); b1p += __shfl_xor(b1p, 2);
    hdp += __shfl_xor(hdp, 1); hdp += __shfl_xor(hdp, 2);
    if (pq == 0) { pb1[ry * HH_ + n0 + il] = b1p; phd[ry * HH_ + n0 + il] = hdp; }
}

// ============ K2: part[kb][i][j] = sum_{k chunk 384} Mt[i][k]*Xt[j][k], bf16 MFMA ====
// grid (4 jblk, 8 iblk, 16 kb); block 64i x 64j, 4 waves of 32x32
__global__ __launch_bounds__(256) void k_gemm2(
    const short* __restrict__ Mt, const short* __restrict__ Xt,
    float* __restrict__ part) {
    __shared__ short As[64 * 32], Bs[64 * 32];
    const int t = threadIdx.x;
    const int j0 = blockIdx.x * 64;
    const int i0 = blockIdx.y * 64;
    const int kb = blockIdx.z;
    const int row = t >> 2, q = t & 3;
    const int l = t & 63, w = t >> 6;
    const int wm = w >> 1, wn = w & 1;
    const int lm = l & 15, g = l >> 4;
    const int sw = swz4(row, q);
    f32x4 acc[2][2] = {};
    for (int ks = 0; ks < 12; ++ks) {
        const int k0 = kb * 384 + ks * 32;
        *(bf16x8s*)(&As[(row * 4 + sw) * 8]) =
            *(const bf16x8s*)(&Mt[(size_t)(i0 + row) * 6144 + k0 + q * 8]);
        *(bf16x8s*)(&Bs[(row * 4 + sw) * 8]) =
            *(const bf16x8s*)(&Xt[(size_t)(j0 + row) * 6144 + k0 + q * 8]);
        __syncthreads();
        bf16x8s a[2], b[2];
        #pragma unroll
        for (int mi = 0; mi < 2; ++mi) {
            int r = wm * 32 + mi * 16 + lm;
            a[mi] = *(const bf16x8s*)(&As[(r * 4 + swz4(r, g)) * 8]);
        }
        #pragma unroll
        for (int nj = 0; nj < 2; ++nj) {
            int r = wn * 32 + nj * 16 + lm;
            b[nj] = *(const bf16x8s*)(&Bs[(r * 4 + swz4(r, g)) * 8]);
        }
        #pragma unroll
        for (int mi = 0; mi < 2; ++mi)
            #pragma unroll
            for (int nj = 0; nj < 2; ++nj)
                acc[mi][nj] = __builtin_amdgcn_mfma_f32_16x16x32_bf16(a[mi], b[nj], acc[mi][nj], 0, 0, 0);
        __syncthreads();
    }
    #pragma unroll
    for (int mi = 0; mi < 2; ++mi)
        #pragma unroll
        for (int nj = 0; nj < 2; ++nj) {
            int j = j0 + wn * 32 + nj * 16 + lm;
            #pragma unroll
            for (int qq = 0; qq < 4; ++qq) {
                int i = i0 + wm * 32 + mi * 16 + g * 4 + qq;
                part[((size_t)kb * HH_ + i) * DD_ + j] = acc[mi][nj][qq];
            }
        }
}

// ============ K3: reductions + broadcast + zeros ============
__global__ void k_tail(const float* __restrict__ part, const float* __restrict__ pb1,
                       const float* __restrict__ phd, float* __restrict__ out) {
    int gid = blockIdx.x * 256 + threadIdx.x;
    const int HD = HH_ * DD_;   // 131072
    if (gid < HD) {
        float sv = 0.f;
        #pragma unroll
        for (int kb = 0; kb < 16; ++kb) sv += part[(size_t)kb * HD + gid];
        out[gid] = sv;
    } else if (gid < HD + HH_) {
        int i = gid - HD;
        float sv = 0.f;
        #pragma unroll
        for (int kb = 0; kb < 64; ++kb) sv += pb1[kb * HH_ + i];
        out[gid] = sv;
    } else if (gid < HD + HH_ + OO_ * HH_) {
        int i = (gid - HD - HH_) & (HH_ - 1);
        float sv = 0.f;
        #pragma unroll
        for (int kb = 0; kb < 64; ++kb) sv += phd[kb * HH_ + i];
        out[gid] = sv;
    } else if (gid < HD + HH_ + OO_ * HH_ + OO_) {
        out[gid] = 0.f;
    }
}

extern "C" void kernel_launch(void* const* d_in, const int* in_sizes, int n_in,
                              void* d_out, int out_size, void* d_ws, size_t ws_size,
                              hipStream_t stream) {
    const float* x  = (const float*)d_in[0];
    const float* W1 = (const float*)d_in[1];
    const float* b1 = (const float*)d_in[2];
    const float* W2 = (const float*)d_in[3];
    // d_in[4] = b2 (unused: b2 Jacobians cancel)
    const int* ap = (const int*)d_in[5];
    const int* pI = (const int*)d_in[6];
    const int* an = (const int*)d_in[7];
    const int* nI = (const int*)d_in[8];
    float* out = (float*)d_out;
    float* ws = (float*)d_ws;

    // workspace (float units): total ~4.66M floats = 18.6 MB
    float* part = ws;                         // 16*131072 = 2097152
    short* Mt   = (short*)(ws + 2097152);     // 512*6144 shorts = 1572864 floats
    short* Xt   = (short*)(ws + 3670016);     // 256*6144 shorts =  786432 floats
    float* pb1  = ws + 4456448;               // 64*512 = 32768
    float* phd  = ws + 4489216;               // 64*512 = 32768
    short* w1hi = (short*)(ws + 4521984);     // 512*256 shorts = 65536 floats
    short* w1lo = (short*)(ws + 4587520);
    float* c    = ws + 4653056;               // 512

    k_prep<<<dim3(146), dim3(256), 0, stream>>>(x, W1, W2, ap, pI, an, nI,
                                                w1hi, w1lo, c, Xt);
    k_fused1<<<dim3(8, 64), dim3(256), 0, stream>>>(x, w1hi, w1lo, b1, c,
                                                    ap, pI, an, nI, Mt, pb1, phd);
    k_gemm2<<<dim3(4, 8, 16), dim3(256), 0, stream>>>(Mt, Xt, part);
    k_tail<<<dim3(643), dim3(256), 0, stream>>>(part, pb1, phd, out);
}

// Round 6
// 33.196 us; speedup vs baseline: 1.2601x; 1.0849x over previous
//
#include <hip/hip_runtime.h>
#include <math.h>

#define DD_ 256
#define HH_ 512
#define OO_ 64

typedef __attribute__((ext_vector_type(8))) short bf16x8s;
typedef __attribute__((ext_vector_type(4))) float f32x4;

__device__ __forceinline__ unsigned short f2bf(float f) {
    unsigned u = __float_as_uint(f);
    u += 0x7FFF + ((u >> 16) & 1);   // round-to-nearest-even
    return (unsigned short)(u >> 16);
}
__device__ __forceinline__ float bf2f(unsigned short h) {
    return __uint_as_float(((unsigned)h) << 16);
}
// XOR swizzle of the 16B slot within a 64B LDS row: 2-way-max bank aliasing
__device__ __forceinline__ int swz4(int r, int g) {
    return g ^ (r & 3) ^ ((r >> 2) & 3);
}

// ============ L1 mega-kernel ============
// bb < 512: fused gemm1 + tanh + build Mt + b1/hd partials (self-contained:
//           converts W1 inline, computes c inline). n0=(bb&7)*64, ry=bb>>3.
// bb >= 512: build Xt[256][6144] bf16 (independent work, same launch).
__global__ __launch_bounds__(256) void k_mega(
    const float* __restrict__ x, const float* __restrict__ W1,
    const float* __restrict__ b1, const float* __restrict__ W2,
    const int* __restrict__ ap, const int* __restrict__ pI,
    const int* __restrict__ an, const int* __restrict__ nI,
    short* __restrict__ Mt, short* __restrict__ Xt,
    float* __restrict__ pb1, float* __restrict__ phd) {
    const int t = threadIdx.x;
    const int bb = blockIdx.x;
    if (bb < 512) {
        __shared__ short Ah[64 * 32], Al[64 * 32], Bh[64 * 32], Bl[64 * 32];
        __shared__ float ht[64][67];   // pad 67: pair-read stride 67 -> conflict-free
        __shared__ int sidx[64];
        const int n0 = (bb & 7) * 64;
        const int ry = bb >> 3;
        const int s = ry >> 5;
        const int p0 = (ry & 31) * 32;
        const int* IA = s ? an : ap;
        const int* IB = s ? nI : pI;
        if (t < 32) sidx[t] = IA[p0 + t];
        else if (t < 64) sidx[t] = IB[p0 + t - 32];
        __syncthreads();
        const int row = t >> 2, q = t & 3;          // staging: row 0..63, 16B slot 0..3
        const int l = t & 63, w = t >> 6;
        const int wm = w >> 1, wn = w & 1;          // wave 2x2 over 64x64 tile
        const int lm = l & 15, g = l >> 4;          // frag: m/n = lm, k-slot = g
        const int sw = swz4(row, q);
        f32x4 acc[2][2] = {};
        for (int k0 = 0; k0 < DD_; k0 += 32) {
            {   // stage A: gathered x rows, fp32 -> bf16 hi/lo on the fly
                const float* src = x + (size_t)sidx[row] * DD_ + k0 + q * 8;
                float4 v0 = *(const float4*)src;
                float4 v1 = *(const float4*)(src + 4);
                float f[8] = {v0.x, v0.y, v0.z, v0.w, v1.x, v1.y, v1.z, v1.w};
                bf16x8s hi, lo;
                #pragma unroll
                for (int e = 0; e < 8; ++e) {
                    unsigned short hh = f2bf(f[e]);
                    hi[e] = (short)hh;
                    lo[e] = (short)f2bf(f[e] - bf2f(hh));
                }
                *(bf16x8s*)(&Ah[(row * 4 + sw) * 8]) = hi;
                *(bf16x8s*)(&Al[(row * 4 + sw) * 8]) = lo;
            }
            {   // stage B: W1 rows, fp32 -> bf16 hi/lo on the fly
                const float* src = W1 + (size_t)(n0 + row) * DD_ + k0 + q * 8;
                float4 v0 = *(const float4*)src;
                float4 v1 = *(const float4*)(src + 4);
                float f[8] = {v0.x, v0.y, v0.z, v0.w, v1.x, v1.y, v1.z, v1.w};
                bf16x8s hi, lo;
                #pragma unroll
                for (int e = 0; e < 8; ++e) {
                    unsigned short hh = f2bf(f[e]);
                    hi[e] = (short)hh;
                    lo[e] = (short)f2bf(f[e] - bf2f(hh));
                }
                *(bf16x8s*)(&Bh[(row * 4 + sw) * 8]) = hi;
                *(bf16x8s*)(&Bl[(row * 4 + sw) * 8]) = lo;
            }
            __syncthreads();
            bf16x8s ah[2], al[2], bh[2], bl[2];
            #pragma unroll
            for (int mi = 0; mi < 2; ++mi) {
                int r = wm * 32 + mi * 16 + lm;
                ah[mi] = *(const bf16x8s*)(&Ah[(r * 4 + swz4(r, g)) * 8]);
                al[mi] = *(const bf16x8s*)(&Al[(r * 4 + swz4(r, g)) * 8]);
            }
            #pragma unroll
            for (int nj = 0; nj < 2; ++nj) {
                int r = wn * 32 + nj * 16 + lm;
                bh[nj] = *(const bf16x8s*)(&Bh[(r * 4 + swz4(r, g)) * 8]);
                bl[nj] = *(const bf16x8s*)(&Bl[(r * 4 + swz4(r, g)) * 8]);
            }
            #pragma unroll
            for (int mi = 0; mi < 2; ++mi)
                #pragma unroll
                for (int nj = 0; nj < 2; ++nj) {
                    acc[mi][nj] = __builtin_amdgcn_mfma_f32_16x16x32_bf16(ah[mi], bh[nj], acc[mi][nj], 0, 0, 0);
                    acc[mi][nj] = __builtin_amdgcn_mfma_f32_16x16x32_bf16(ah[mi], bl[nj], acc[mi][nj], 0, 0, 0);
                    acc[mi][nj] = __builtin_amdgcn_mfma_f32_16x16x32_bf16(al[mi], bh[nj], acc[mi][nj], 0, 0, 0);
                }
            __syncthreads();
        }
        // h-tile -> LDS (tanh applied); r<32 = a-side, r>=32 = b-side
        #pragma unroll
        for (int mi = 0; mi < 2; ++mi)
            #pragma unroll
            for (int nj = 0; nj < 2; ++nj) {
                int jl = wn * 32 + nj * 16 + lm;
                float bv = b1[n0 + jl];
                #pragma unroll
                for (int qq = 0; qq < 4; ++qq) {
                    int r = wm * 32 + mi * 16 + g * 4 + qq;
                    ht[r][jl] = tanhf(acc[mi][nj][qq] + bv);
                }
            }
        __syncthreads();
        // build M + partials: thread (il = t>>2, pq = t&3) handles 8 pairs of col il
        const int il = t >> 2, pq = t & 3;
        float ci = 0.f;
        #pragma unroll 8
        for (int o = 0; o < OO_; ++o) { float wv = W2[o * HH_ + n0 + il]; ci += wv * wv; }
        const float sgn = s ? -1.f : 1.f;
        float b1p = 0.f, hdp = 0.f;
        bf16x8s v0, v1, v2;
        #pragma unroll
        for (int pp = 0; pp < 8; ++pp) {
            int pl = pq * 8 + pp;
            float ha = ht[pl][il];
            float hb = ht[pl + 32][il];
            float da = 1.f - ha * ha, db = 1.f - hb * hb;
            float s11 = sgn * (da * da * ci);
            float s12 = sgn * (-2.f * da * db * ci);
            float s22 = sgn * (db * db * ci);
            v0[pp] = (short)f2bf(s11);
            v1[pp] = (short)f2bf(s12);
            v2[pp] = (short)f2bf(s22);
            b1p += s11 + s12 + s22;
            float d = ha - hb;
            hdp += sgn * d * d;
        }
        size_t base = (size_t)(n0 + il) * 6144 + s * 1024 + p0 + pq * 8;
        *(bf16x8s*)(&Mt[base]) = v0;
        *(bf16x8s*)(&Mt[base + 2048]) = v1;
        *(bf16x8s*)(&Mt[base + 4096]) = v2;
        b1p += __shfl_xor(b1p, 1); b1p += __shfl_xor(b1p, 2);
        hdp += __shfl_xor(hdp, 1); hdp += __shfl_xor(hdp, 2);
        if (pq == 0) { pb1[ry * HH_ + n0 + il] = b1p; phd[ry * HH_ + n0 + il] = hdp; }
    } else {
        __shared__ int sia[64], sib[64];
        const int b2 = bb - 512;
        const int jblk = b2 >> 5, pblk = b2 & 31;
        const int j = jblk * 64 + (t >> 2), pq = t & 3;
        const int p0 = pblk * 64;
        const int s = p0 >> 10;
        const int* IA = s ? an : ap;
        const int* IB = s ? nI : pI;
        if (t < 64) sia[t] = IA[(p0 & 1023) + t];
        else if (t < 128) sib[t - 64] = IB[(p0 & 1023) + (t - 64)];
        __syncthreads();
        short xv[3][16];
        #pragma unroll
        for (int pp = 0; pp < 16; ++pp) {
            int pl = pq * 16 + pp;
            float xa = x[(size_t)sia[pl] * DD_ + j];
            float xb = x[(size_t)sib[pl] * DD_ + j];
            xv[0][pp] = (short)f2bf(xa * xa);
            xv[1][pp] = (short)f2bf(xa * xb);
            xv[2][pp] = (short)f2bf(xb * xb);
        }
        size_t base = (size_t)j * 6144 + p0 + pq * 16;
        #pragma unroll
        for (int term = 0; term < 3; ++term) {
            bf16x8s v0, v1;
            #pragma unroll
            for (int e = 0; e < 8; ++e) { v0[e] = xv[term][e]; v1[e] = xv[term][e + 8]; }
            *(bf16x8s*)(&Xt[base + (size_t)term * 2048]) = v0;
            *(bf16x8s*)(&Xt[base + (size_t)term * 2048 + 8]) = v1;
        }
    }
}

// ============ L2: part[kb][i][j] = sum_{k chunk 384} Mt[i][k]*Xt[j][k], bf16 MFMA ====
// grid (4 jblk, 8 iblk, 16 kb); block 64i x 64j, 4 waves of 32x32
__global__ __launch_bounds__(256) void k_gemm2(
    const short* __restrict__ Mt, const short* __restrict__ Xt,
    float* __restrict__ part) {
    __shared__ short As[64 * 32], Bs[64 * 32];
    const int t = threadIdx.x;
    const int j0 = blockIdx.x * 64;
    const int i0 = blockIdx.y * 64;
    const int kb = blockIdx.z;
    const int row = t >> 2, q = t & 3;
    const int l = t & 63, w = t >> 6;
    const int wm = w >> 1, wn = w & 1;
    const int lm = l & 15, g = l >> 4;
    const int sw = swz4(row, q);
    f32x4 acc[2][2] = {};
    for (int ks = 0; ks < 12; ++ks) {
        const int k0 = kb * 384 + ks * 32;
        *(bf16x8s*)(&As[(row * 4 + sw) * 8]) =
            *(const bf16x8s*)(&Mt[(size_t)(i0 + row) * 6144 + k0 + q * 8]);
        *(bf16x8s*)(&Bs[(row * 4 + sw) * 8]) =
            *(const bf16x8s*)(&Xt[(size_t)(j0 + row) * 6144 + k0 + q * 8]);
        __syncthreads();
        bf16x8s a[2], b[2];
        #pragma unroll
        for (int mi = 0; mi < 2; ++mi) {
            int r = wm * 32 + mi * 16 + lm;
            a[mi] = *(const bf16x8s*)(&As[(r * 4 + swz4(r, g)) * 8]);
        }
        #pragma unroll
        for (int nj = 0; nj < 2; ++nj) {
            int r = wn * 32 + nj * 16 + lm;
            b[nj] = *(const bf16x8s*)(&Bs[(r * 4 + swz4(r, g)) * 8]);
        }
        #pragma unroll
        for (int mi = 0; mi < 2; ++mi)
            #pragma unroll
            for (int nj = 0; nj < 2; ++nj)
                acc[mi][nj] = __builtin_amdgcn_mfma_f32_16x16x32_bf16(a[mi], b[nj], acc[mi][nj], 0, 0, 0);
        __syncthreads();
    }
    #pragma unroll
    for (int mi = 0; mi < 2; ++mi)
        #pragma unroll
        for (int nj = 0; nj < 2; ++nj) {
            int j = j0 + wn * 32 + nj * 16 + lm;
            #pragma unroll
            for (int qq = 0; qq < 4; ++qq) {
                int i = i0 + wm * 32 + mi * 16 + g * 4 + qq;
                part[((size_t)kb * HH_ + i) * DD_ + j] = acc[mi][nj][qq];
            }
        }
}

// ============ L3: reductions + broadcast + zeros ============
__global__ void k_tail(const float* __restrict__ part, const float* __restrict__ pb1,
                       const float* __restrict__ phd, float* __restrict__ out) {
    int gid = blockIdx.x * 256 + threadIdx.x;
    const int HD = HH_ * DD_;   // 131072
    if (gid < HD) {
        float sv = 0.f;
        #pragma unroll
        for (int kb = 0; kb < 16; ++kb) sv += part[(size_t)kb * HD + gid];
        out[gid] = sv;
    } else if (gid < HD + HH_) {
        int i = gid - HD;
        float sv = 0.f;
        #pragma unroll
        for (int kb = 0; kb < 64; ++kb) sv += pb1[kb * HH_ + i];
        out[gid] = sv;
    } else if (gid < HD + HH_ + OO_ * HH_) {
        int i = (gid - HD - HH_) & (HH_ - 1);
        float sv = 0.f;
        #pragma unroll
        for (int kb = 0; kb < 64; ++kb) sv += phd[kb * HH_ + i];
        out[gid] = sv;
    } else if (gid < HD + HH_ + OO_ * HH_ + OO_) {
        out[gid] = 0.f;
    }
}

extern "C" void kernel_launch(void* const* d_in, const int* in_sizes, int n_in,
                              void* d_out, int out_size, void* d_ws, size_t ws_size,
                              hipStream_t stream) {
    const float* x  = (const float*)d_in[0];
    const float* W1 = (const float*)d_in[1];
    const float* b1 = (const float*)d_in[2];
    const float* W2 = (const float*)d_in[3];
    // d_in[4] = b2 (unused: b2 Jacobians cancel)
    const int* ap = (const int*)d_in[5];
    const int* pI = (const int*)d_in[6];
    const int* an = (const int*)d_in[7];
    const int* nI = (const int*)d_in[8];
    float* out = (float*)d_out;
    float* ws = (float*)d_ws;

    // workspace (float units): total ~4.52M floats = 18.1 MB
    float* part = ws;                         // 16*131072 = 2097152
    short* Mt   = (short*)(ws + 2097152);     // 512*6144 shorts = 1572864 floats
    short* Xt   = (short*)(ws + 3670016);     // 256*6144 shorts =  786432 floats
    float* pb1  = ws + 4456448;               // 64*512 = 32768
    float* phd  = ws + 4489216;               // 64*512 = 32768

    k_mega<<<dim3(640), dim3(256), 0, stream>>>(x, W1, b1, W2, ap, pI, an, nI,
                                                Mt, Xt, pb1, phd);
    k_gemm2<<<dim3(4, 8, 16), dim3(256), 0, stream>>>(Mt, Xt, part);
    k_tail<<<dim3(643), dim3(256), 0, stream>>>(part, pb1, phd, out);
}